// Round 1
// baseline (2426.059 us; speedup 1.0000x reference)
//
#include <hip/hip_runtime.h>
#include <math.h>

// Dims (fixed by problem): B=64, N=1024, M=32, T=25, R=512, SO=512, OD=10
#define TRW 57  // trace ring width = M + T

template<int NT>
__device__ __forceinline__ float block_sum(float v, float* sh) {
  int t = threadIdx.x;
  sh[t] = v;
  __syncthreads();
  #pragma unroll
  for (int s = NT >> 1; s > 0; s >>= 1) {
    if (t < s) sh[t] += sh[t + s];
    __syncthreads();
  }
  float r = sh[0];
  __syncthreads();
  return r;
}

__device__ __forceinline__ float sigmoidf(float x) {
  return 1.f / (1.f + expf(-x));
}

// ---------------- encoder ----------------

__global__ void k_enc1(const float* __restrict__ x, const float* __restrict__ w,
                       const float* __restrict__ bias, const float* __restrict__ g,
                       const float* __restrict__ bn, float* __restrict__ out) {
  int b = blockIdx.x, o = threadIdx.x;  // 128 threads
  __shared__ float xs[784];
  __shared__ float red[128];
  for (int i = o; i < 784; i += 128) xs[i] = x[b * 784 + i];
  __syncthreads();
  float s = bias[o];
  const float* wr = w + o * 784;
  for (int k = 0; k < 784; k++) s += xs[k] * wr[k];
  float mu = block_sum<128>(s, red) * (1.f / 128.f);
  float d = s - mu;
  float var = block_sum<128>(d * d, red) * (1.f / 128.f);
  float y = d / sqrtf(var + 1e-5f) * g[o] + bn[o];
  out[b * 128 + o] = fmaxf(y, 0.f);
}

__global__ void k_enc2(const float* __restrict__ h1, const float* __restrict__ w,
                       const float* __restrict__ bias, const float* __restrict__ g,
                       const float* __restrict__ bn, float* __restrict__ out) {
  int b = blockIdx.x, o = threadIdx.x;  // 64 threads
  __shared__ float hs[128];
  __shared__ float red[64];
  hs[o] = h1[b * 128 + o];
  hs[o + 64] = h1[b * 128 + o + 64];
  __syncthreads();
  float s = bias[o];
  const float* wr = w + o * 128;
  for (int k = 0; k < 128; k++) s += hs[k] * wr[k];
  float mu = block_sum<64>(s, red) * (1.f / 64.f);
  float d = s - mu;
  float var = block_sum<64>(d * d, red) * (1.f / 64.f);
  float y = d / sqrtf(var + 1e-5f) * g[o] + bn[o];
  out[b * 64 + o] = fmaxf(y, 0.f);
}

// enc -> kv(LN) -> v -> attn_out, all within one block per batch row
__global__ void k_attn(const float* __restrict__ h2,
                       const float* __restrict__ w3, const float* __restrict__ b3,
                       const float* __restrict__ kvw, const float* __restrict__ kvb,
                       const float* __restrict__ kvg, const float* __restrict__ kvbn,
                       const float* __restrict__ ipw, const float* __restrict__ ipb,
                       const float* __restrict__ opw, const float* __restrict__ opb,
                       float* __restrict__ attn) {
  int b = blockIdx.x, o = threadIdx.x;  // 512 threads
  __shared__ float h2s[64];
  __shared__ float encs[512];
  __shared__ float kvs[512];
  __shared__ float vs[512];
  __shared__ float red[512];
  if (o < 64) h2s[o] = h2[b * 64 + o];
  __syncthreads();
  float e = b3[o];
  {
    const float* wr = w3 + o * 64;
    for (int k = 0; k < 64; k++) e += h2s[k] * wr[k];
  }
  encs[o] = e;
  __syncthreads();
  float kvp = kvb[o];
  {
    const float* wr = kvw + o * 512;
    for (int k = 0; k < 512; k++) kvp += encs[k] * wr[k];
  }
  float mu = block_sum<512>(kvp, red) * (1.f / 512.f);
  float d = kvp - mu;
  float var = block_sum<512>(d * d, red) * (1.f / 512.f);
  kvs[o] = d / sqrtf(var + 1e-5f) * kvg[o] + kvbn[o];
  __syncthreads();
  float v = ipb[1024 + o];  // Wv = in_proj rows [2R:3R) = [1024:1536)
  {
    const float* wr = ipw + (1024 + o) * 512;
    for (int k = 0; k < 512; k++) v += kvs[k] * wr[k];
  }
  vs[o] = v;
  __syncthreads();
  float a = opb[o];
  {
    const float* wr = opw + o * 512;
    for (int k = 0; k < 512; k++) a += vs[k] * wr[k];
  }
  attn[b * 512 + o] = a;
}

// ---------------- state init ----------------

__global__ void k_init_trace(const float* __restrict__ st, float* __restrict__ trace) {
  int i = blockIdx.x * 256 + threadIdx.x;  // < 64*1024*32
  int j = i & 31;
  int rest = i >> 5;  // = b*1024 + n
  trace[rest * TRW + j] = st[(rest & 1023) * 32 + j];
}

__global__ void k_init_state(const float* __restrict__ sas, const int* __restrict__ il,
                             const int* __restrict__ ir, float* __restrict__ act,
                             float* __restrict__ aO, float* __restrict__ bO) {
  int i = blockIdx.x * 256 + threadIdx.x;  // < 65536
  act[i] = sas[i & 1023];
  if (i < 64 * 512) {
    int o = i & 511;
    aO[i] = sas[il[o]] * sas[ir[o]];
    bO[i] = 1.f;
  }
}

// ---------------- per-step kernels ----------------

// C(64 x 2048) = pre(64 x 1536) @ syn_w^T, split-K into 8 chunks -> partials
__global__ __launch_bounds__(256) void k_syn_mm(const float* __restrict__ attn,
                                                const float* __restrict__ act,
                                                const float* __restrict__ synw,
                                                float* __restrict__ part) {
  int ct = blockIdx.x;  // 0..31 column tile (64 cols each)
  int kc = blockIdx.y;  // 0..7 k chunk (192 each)
  int tid = threadIdx.x;
  int tb = tid >> 4, tc = tid & 15;
  int b0 = tb * 4, c0 = tc * 4;
  __shared__ __align__(16) float pre_t[32 * 68];
  __shared__ __align__(16) float w_lds[32 * 68];
  float acc[4][4];
  #pragma unroll
  for (int i = 0; i < 4; i++)
    #pragma unroll
    for (int j = 0; j < 4; j++) acc[i][j] = 0.f;

  for (int kt = 0; kt < 192; kt += 32) {
    int k0 = kc * 192 + kt;
    #pragma unroll
    for (int r = 0; r < 8; r++) {
      int idx = r * 256 + tid;  // < 2048
      int kk = idx & 31;
      int bb = idx >> 5;  // 0..63, also used as column index for W tile
      int kg = k0 + kk;
      float pv = (kg < 512) ? attn[bb * 512 + kg] : act[bb * 1024 + (kg - 512)];
      pre_t[kk * 68 + bb] = pv;
      w_lds[kk * 68 + bb] = synw[(ct * 64 + bb) * 1536 + kg];
    }
    __syncthreads();
    #pragma unroll 8
    for (int kk = 0; kk < 32; kk++) {
      float4 av = *(const float4*)(pre_t + kk * 68 + b0);
      float4 wv = *(const float4*)(w_lds + kk * 68 + c0);
      float a[4] = {av.x, av.y, av.z, av.w};
      float w[4] = {wv.x, wv.y, wv.z, wv.w};
      #pragma unroll
      for (int i = 0; i < 4; i++)
        #pragma unroll
        for (int j = 0; j < 4; j++) acc[i][j] += a[i] * w[j];
    }
    __syncthreads();
  }
  float* pb = part + kc * (64 * 2048);
  #pragma unroll
  for (int i = 0; i < 4; i++) {
    float4 st4 = make_float4(acc[i][0], acc[i][1], acc[i][2], acc[i][3]);
    *(float4*)(pb + (b0 + i) * 2048 + ct * 64 + c0) = st4;
  }
}

// sum partials + bias -> GLU -> LN(1024) -> write trace column 32+t
__global__ __launch_bounds__(1024) void k_syn_ln(const float* __restrict__ part,
                                                 const float* __restrict__ synb,
                                                 const float* __restrict__ sg,
                                                 const float* __restrict__ sbn,
                                                 float* __restrict__ trace, int t) {
  int b = blockIdx.x, n = threadIdx.x;
  __shared__ float red[1024];
  float a = synb[n], g = synb[n + 1024];
  #pragma unroll
  for (int kc = 0; kc < 8; kc++) {
    const float* pb = part + kc * (64 * 2048) + b * 2048;
    a += pb[n];
    g += pb[n + 1024];
  }
  float val = a * sigmoidf(g);
  float mu = block_sum<1024>(val, red) * (1.f / 1024.f);
  float d = val - mu;
  float var = block_sum<1024>(d * d, red) * (1.f / 1024.f);
  float ns = d / sqrtf(var + 1e-5f) * sg[n] + sbn[n];
  trace[(b * 1024 + n) * TRW + 32 + t] = ns;
}

// per-n: hh = glu(trace_win(64x32) @ w1[n](32x256) + b1[n]); act = hh @ w2[n] + b2[n]
__global__ __launch_bounds__(256) void k_nlm(const float* __restrict__ trace,
                                             const float* __restrict__ w1,
                                             const float* __restrict__ b1,
                                             const float* __restrict__ w2,
                                             const float* __restrict__ b2,
                                             float* __restrict__ act, int t) {
  int n = blockIdx.x;
  int tid = threadIdx.x;
  int tb = tid >> 5;    // 0..7 -> b range tb*8..tb*8+8
  int tjj = tid & 31;   // 0..31 -> j = tjj + 32*jj (bank-conflict-free)
  __shared__ __align__(16) float At[32 * 68];  // [m][b]
  __shared__ float w1s[32 * 256];              // [m][h]
  __shared__ float b1s[256];
  __shared__ float w2s[128];

  #pragma unroll
  for (int r = 0; r < 8; r++) {
    int idx = r * 256 + tid;  // < 2048
    int m = idx >> 6, bb = idx & 63;
    At[m * 68 + bb] = trace[(bb * 1024 + n) * TRW + (t + 1) + m];
  }
  const float* w1n = w1 + n * 8192;
  #pragma unroll
  for (int r = 0; r < 32; r++) {
    int idx = r * 256 + tid;
    w1s[idx] = w1n[idx];
  }
  b1s[tid] = b1[n * 256 + tid];
  if (tid < 128) w2s[tid] = w2[n * 128 + tid];
  __syncthreads();

  float h[8][8];
  #pragma unroll
  for (int jj = 0; jj < 8; jj++) {
    float bv = b1s[tjj + 32 * jj];
    #pragma unroll
    for (int i = 0; i < 8; i++) h[i][jj] = bv;
  }
  for (int m = 0; m < 32; m++) {
    float4 a0 = *(const float4*)(At + m * 68 + tb * 8);
    float4 a1 = *(const float4*)(At + m * 68 + tb * 8 + 4);
    float a[8] = {a0.x, a0.y, a0.z, a0.w, a1.x, a1.y, a1.z, a1.w};
    float w[8];
    #pragma unroll
    for (int jj = 0; jj < 8; jj++) w[jj] = w1s[m * 256 + tjj + 32 * jj];
    #pragma unroll
    for (int i = 0; i < 8; i++)
      #pragma unroll
      for (int jj = 0; jj < 8; jj++) h[i][jj] += a[i] * w[jj];
  }
  float b2n = b2[n];
  #pragma unroll
  for (int i = 0; i < 8; i++) {
    float p = 0.f;
    #pragma unroll
    for (int jj = 0; jj < 4; jj++) {
      // pair (j, j+128): j = tjj+32*jj (jj<4), j+128 = tjj+32*(jj+4)
      float hh = h[i][jj] * sigmoidf(h[i][jj + 4]);
      p += hh * w2s[tjj + 32 * jj];
    }
    #pragma unroll
    for (int off = 16; off > 0; off >>= 1) p += __shfl_xor(p, off, 64);
    if (tjj == 0) act[(tb * 8 + i) * 1024 + n] = p + b2n;
  }
}

// sync-out update + op layer1 (LN256+relu)
__global__ __launch_bounds__(512) void k_op1(const float* __restrict__ act,
                                             const float* __restrict__ decay,
                                             const int* __restrict__ il, const int* __restrict__ ir,
                                             float* __restrict__ aO, float* __restrict__ bO,
                                             const float* __restrict__ w1, const float* __restrict__ bb1,
                                             const float* __restrict__ g1, const float* __restrict__ bn1,
                                             float* __restrict__ p1) {
  int b = blockIdx.x, o = threadIdx.x;  // 512
  __shared__ float so[512];
  __shared__ float red[512];
  float r = expf(-fminf(fmaxf(decay[o], 0.f), 15.f));
  float pp = act[b * 1024 + il[o]] * act[b * 1024 + ir[o]];
  float a = r * aO[b * 512 + o] + pp;
  float bb = r * bO[b * 512 + o] + 1.f;
  aO[b * 512 + o] = a;
  bO[b * 512 + o] = bb;
  so[o] = a / sqrtf(bb + 1e-8f);
  __syncthreads();
  float p = 0.f;
  if (o < 256) {
    p = bb1[o];
    const float* wr = w1 + o * 512;
    for (int k = 0; k < 512; k++) p += so[k] * wr[k];
  }
  float mu = block_sum<512>((o < 256) ? p : 0.f, red) * (1.f / 256.f);
  float d = (o < 256) ? (p - mu) : 0.f;
  float var = block_sum<512>(d * d, red) * (1.f / 256.f);
  if (o < 256) {
    float y = d / sqrtf(var + 1e-5f) * g1[o] + bn1[o];
    p1[b * 256 + o] = fmaxf(y, 0.f);
  }
}

// op layer2 (LN64+relu) + layer3 + softmax entropy + write outputs
__global__ __launch_bounds__(64) void k_op23(const float* __restrict__ p1,
                                             const float* __restrict__ w2, const float* __restrict__ bb2,
                                             const float* __restrict__ g2, const float* __restrict__ bn2,
                                             const float* __restrict__ w3, const float* __restrict__ bb3,
                                             float* __restrict__ out, int t) {
  int b = blockIdx.x, o = threadIdx.x;  // 64
  __shared__ float p1s[256];
  __shared__ float p2s[64];
  __shared__ float preds[10];
  __shared__ float red[64];
  #pragma unroll
  for (int r = 0; r < 4; r++) p1s[r * 64 + o] = p1[b * 256 + r * 64 + o];
  __syncthreads();
  float p = bb2[o];
  {
    const float* wr = w2 + o * 256;
    for (int k = 0; k < 256; k++) p += p1s[k] * wr[k];
  }
  float mu = block_sum<64>(p, red) * (1.f / 64.f);
  float d = p - mu;
  float var = block_sum<64>(d * d, red) * (1.f / 64.f);
  float y = d / sqrtf(var + 1e-5f) * g2[o] + bn2[o];
  p2s[o] = fmaxf(y, 0.f);
  __syncthreads();
  if (o < 10) {
    float pr = bb3[o];
    const float* wr = w3 + o * 64;
    for (int k = 0; k < 64; k++) pr += p2s[k] * wr[k];
    preds[o] = pr;
    out[b * 250 + o * 25 + t] = pr;  // predictions (B, OD, T)
  }
  __syncthreads();
  if (o == 0) {
    float mx = preds[0];
    for (int k = 1; k < 10; k++) mx = fmaxf(mx, preds[k]);
    float s = 0.f;
    float e[10];
    for (int k = 0; k < 10; k++) { e[k] = expf(preds[k] - mx); s += e[k]; }
    float ent = 0.f;
    for (int k = 0; k < 10; k++) {
      float pr = e[k] / s;
      ent -= pr * logf(pr + 1e-10f);
    }
    ent *= (1.f / 2.3025851f);  // / log(10)
    out[16000 + b * 50 + t] = ent;          // certainties (B, 2, T)
    out[16000 + b * 50 + 25 + t] = 1.f - ent;
  }
}

extern "C" void kernel_launch(void* const* d_in, const int* in_sizes, int n_in,
                              void* d_out, int out_size, void* d_ws, size_t ws_size,
                              hipStream_t stream) {
  const float* x        = (const float*)d_in[0];
  const float* sas      = (const float*)d_in[1];
  const float* st       = (const float*)d_in[2];
  const float* ie_w1    = (const float*)d_in[3];
  const float* ie_b1    = (const float*)d_in[4];
  const float* ie_g1    = (const float*)d_in[5];
  const float* ie_bn1   = (const float*)d_in[6];
  const float* ie_w2    = (const float*)d_in[7];
  const float* ie_b2    = (const float*)d_in[8];
  const float* ie_g2    = (const float*)d_in[9];
  const float* ie_bn2   = (const float*)d_in[10];
  const float* ie_w3    = (const float*)d_in[11];
  const float* ie_b3    = (const float*)d_in[12];
  const float* kv_w     = (const float*)d_in[13];
  const float* kv_b     = (const float*)d_in[14];
  const float* kv_g     = (const float*)d_in[15];
  const float* kv_bn    = (const float*)d_in[16];
  // d_in[17] q_w, d_in[18] q_b unused by reference
  const float* ip_w     = (const float*)d_in[19];
  const float* ip_b     = (const float*)d_in[20];
  const float* op_w     = (const float*)d_in[21];
  const float* op_b     = (const float*)d_in[22];
  const float* syn_w    = (const float*)d_in[23];
  const float* syn_b    = (const float*)d_in[24];
  const float* syn_g    = (const float*)d_in[25];
  const float* syn_bn   = (const float*)d_in[26];
  const float* nlm_w1   = (const float*)d_in[27];
  const float* nlm_b1   = (const float*)d_in[28];
  const float* nlm_w2   = (const float*)d_in[29];
  const float* nlm_b2   = (const float*)d_in[30];
  // d_in[31] decay_action unused (aA/bA dead in reference)
  const float* decay_o  = (const float*)d_in[32];
  const float* op_w1    = (const float*)d_in[33];
  const float* op_b1    = (const float*)d_in[34];
  const float* op_g1    = (const float*)d_in[35];
  const float* op_bn1   = (const float*)d_in[36];
  const float* op_w2    = (const float*)d_in[37];
  const float* op_b2    = (const float*)d_in[38];
  const float* op_g2    = (const float*)d_in[39];
  const float* op_bn2   = (const float*)d_in[40];
  const float* op_w3    = (const float*)d_in[41];
  const float* op_b3    = (const float*)d_in[42];
  const int* idx_ol     = (const int*)d_in[43];
  const int* idx_or     = (const int*)d_in[44];
  // d_in[45]/[46] idx_act_* unused (aA/bA dead)

  float* out = (float*)d_out;
  float* ws = (float*)d_ws;
  // workspace layout (floats): total ~4.98M floats = ~19.9 MB
  float* h1    = ws;                 // 64*128
  float* h2    = h1 + 8192;          // 64*64
  float* attn  = h2 + 4096;          // 64*512
  float* act   = attn + 32768;       // 64*1024
  float* aO    = act + 65536;        // 64*512
  float* bO    = aO + 32768;         // 64*512
  float* p1    = bO + 32768;         // 64*256
  float* part  = p1 + 16384;         // 8*64*2048
  float* trace = part + 1048576;     // 64*1024*57

  k_enc1<<<64, 128, 0, stream>>>(x, ie_w1, ie_b1, ie_g1, ie_bn1, h1);
  k_enc2<<<64, 64, 0, stream>>>(h1, ie_w2, ie_b2, ie_g2, ie_bn2, h2);
  k_attn<<<64, 512, 0, stream>>>(h2, ie_w3, ie_b3, kv_w, kv_b, kv_g, kv_bn,
                                 ip_w, ip_b, op_w, op_b, attn);
  k_init_trace<<<8192, 256, 0, stream>>>(st, trace);
  k_init_state<<<256, 256, 0, stream>>>(sas, idx_ol, idx_or, act, aO, bO);

  for (int t = 0; t < 25; t++) {
    k_syn_mm<<<dim3(32, 8), 256, 0, stream>>>(attn, act, syn_w, part);
    k_syn_ln<<<64, 1024, 0, stream>>>(part, syn_b, syn_g, syn_bn, trace, t);
    k_nlm<<<1024, 256, 0, stream>>>(trace, nlm_w1, nlm_b1, nlm_w2, nlm_b2, act, t);
    k_op1<<<64, 512, 0, stream>>>(act, decay_o, idx_ol, idx_or, aO, bO,
                                  op_w1, op_b1, op_g1, op_bn1, p1);
    k_op23<<<64, 64, 0, stream>>>(p1, op_w2, op_b2, op_g2, op_bn2, op_w3, op_b3,
                                  out, t);
  }
}

// Round 2
// 2161.463 us; speedup vs baseline: 1.1224x; 1.1224x over previous
//
#include <hip/hip_runtime.h>
#include <math.h>

// Dims (fixed by problem): B=64, N=1024, M=32, T=25, R=512, SO=512, OD=10
#define TRW 57            // trace ring width = M + T
#define TRN (TRW * 64)    // 3648 floats per n: trace layout [n][col][b]

__device__ __forceinline__ float wave_sum(float v) {
  #pragma unroll
  for (int off = 32; off; off >>= 1) v += __shfl_xor(v, off, 64);
  return v;
}

// fused (sum, sumsq) across NT threads; 2 syncthreads total
template<int NT>
__device__ __forceinline__ float2 block_sum2(float a, float b, float2* sh) {
  constexpr int NW = NT / 64;
  a = wave_sum(a); b = wave_sum(b);
  int w = threadIdx.x >> 6, l = threadIdx.x & 63;
  if (l == 0) sh[w] = make_float2(a, b);
  __syncthreads();
  float2 r = make_float2(0.f, 0.f);
  #pragma unroll
  for (int i = 0; i < NW; i++) { r.x += sh[i].x; r.y += sh[i].y; }
  __syncthreads();
  return r;
}

__device__ __forceinline__ float sigmoidf(float x) {
  return 1.f / (1.f + expf(-x));
}

// ---------------- encoder (one-time): wave-per-output GEMV ----------------
// C[b*O+o] = dot(A[b,:K], W[o,:K]) + bias[o]; grid = B*O/4 blocks, 256 thr.
__global__ __launch_bounds__(256) void k_gemv(const float* __restrict__ A,
                                              const float* __restrict__ W,
                                              const float* __restrict__ bias,
                                              float* __restrict__ C, int K, int O) {
  int wid = blockIdx.x * 4 + (threadIdx.x >> 6);
  int lane = threadIdx.x & 63;
  int b = wid / O, o = wid % O;
  const float* a = A + b * K;
  const float* w = W + o * K;
  float s = 0.f;
  for (int k = lane; k < K; k += 64) s += a[k] * w[k];
  s = wave_sum(s);
  if (lane == 0) C[b * O + o] = s + bias[o];
}

template<int O, bool RELU>
__global__ void k_ln(const float* __restrict__ X, const float* __restrict__ g,
                     const float* __restrict__ bn, float* __restrict__ Y) {
  __shared__ float2 sh[O / 64];
  int b = blockIdx.x, o = threadIdx.x;
  float x = X[b * O + o];
  float2 s = block_sum2<O>(x, x * x, sh);
  float mu = s.x * (1.f / O);
  float var = s.y * (1.f / O) - mu * mu;
  float y = (x - mu) * rsqrtf(var + 1e-5f) * g[o] + bn[o];
  if (RELU) y = fmaxf(y, 0.f);
  Y[b * O + o] = y;
}

// ---------------- state init ----------------

__global__ void k_init_trace(const float* __restrict__ st, float* __restrict__ trace) {
  int i = blockIdx.x * 256 + threadIdx.x;  // < 64*1024*32
  int b = i & 63, j = (i >> 6) & 31, n = i >> 11;
  trace[n * TRN + j * 64 + b] = st[n * 32 + j];  // coalesced write
}

__global__ void k_init_state(const float* __restrict__ sas, const int* __restrict__ il,
                             const int* __restrict__ ir, float* __restrict__ act,
                             float* __restrict__ aO, float* __restrict__ bO) {
  int i = blockIdx.x * 256 + threadIdx.x;  // < 65536
  act[i] = sas[i & 1023];
  if (i < 64 * 512) {
    int o = i & 511;
    aO[i] = sas[il[o]] * sas[ir[o]];
    bO[i] = 1.f;
  }
}

// ---------------- per-step kernels ----------------

// C(64 x 2048) = pre(64 x 1536) @ syn_w^T, split-K into 8 chunks -> partials
__global__ __launch_bounds__(256) void k_syn_mm(const float* __restrict__ attn,
                                                const float* __restrict__ act,
                                                const float* __restrict__ synw,
                                                float* __restrict__ part) {
  int ct = blockIdx.x;  // 0..31 column tile (64 cols each)
  int kc = blockIdx.y;  // 0..7 k chunk (192 each)
  int tid = threadIdx.x;
  int tb = tid >> 4, tc = tid & 15;
  int b0 = tb * 4, c0 = tc * 4;
  __shared__ __align__(16) float pre_t[32 * 68];
  __shared__ __align__(16) float w_lds[32 * 68];
  float acc[4][4];
  #pragma unroll
  for (int i = 0; i < 4; i++)
    #pragma unroll
    for (int j = 0; j < 4; j++) acc[i][j] = 0.f;

  for (int kt = 0; kt < 192; kt += 32) {
    int k0 = kc * 192 + kt;
    #pragma unroll
    for (int r = 0; r < 8; r++) {
      int idx = r * 256 + tid;  // < 2048
      int kk = idx & 31;
      int bb = idx >> 5;  // 0..63, also column index for W tile
      int kg = k0 + kk;
      float pv = (kg < 512) ? attn[bb * 512 + kg] : act[bb * 1024 + (kg - 512)];
      pre_t[kk * 68 + bb] = pv;
      w_lds[kk * 68 + bb] = synw[(ct * 64 + bb) * 1536 + kg];
    }
    __syncthreads();
    #pragma unroll 8
    for (int kk = 0; kk < 32; kk++) {
      float4 av = *(const float4*)(pre_t + kk * 68 + b0);
      float4 wv = *(const float4*)(w_lds + kk * 68 + c0);
      float a[4] = {av.x, av.y, av.z, av.w};
      float w[4] = {wv.x, wv.y, wv.z, wv.w};
      #pragma unroll
      for (int i = 0; i < 4; i++)
        #pragma unroll
        for (int j = 0; j < 4; j++) acc[i][j] += a[i] * w[j];
    }
    __syncthreads();
  }
  float* pb = part + kc * (64 * 2048);
  #pragma unroll
  for (int i = 0; i < 4; i++) {
    float4 st4 = make_float4(acc[i][0], acc[i][1], acc[i][2], acc[i][3]);
    *(float4*)(pb + (b0 + i) * 2048 + ct * 64 + c0) = st4;
  }
}

// sum partials + bias -> GLU -> LN(1024) -> write trace column 32+t (layout [n][col][b])
__global__ __launch_bounds__(1024) void k_syn_ln(const float* __restrict__ part,
                                                 const float* __restrict__ synb,
                                                 const float* __restrict__ sg,
                                                 const float* __restrict__ sbn,
                                                 float* __restrict__ trace, int t) {
  __shared__ float2 sh[16];
  int b = blockIdx.x, n = threadIdx.x;
  float a = synb[n], g = synb[n + 1024];
  #pragma unroll
  for (int kc = 0; kc < 8; kc++) {
    const float* pb = part + kc * (64 * 2048) + b * 2048;
    a += pb[n];
    g += pb[n + 1024];
  }
  float val = a * sigmoidf(g);
  float2 s = block_sum2<1024>(val, val * val, sh);
  float mu = s.x * (1.f / 1024.f);
  float var = s.y * (1.f / 1024.f) - mu * mu;
  float ns = (val - mu) * rsqrtf(var + 1e-5f) * sg[n] + sbn[n];
  trace[n * TRN + (32 + t) * 64 + b] = ns;
}

// per-n: hh = glu(trace_win(64x32) @ w1[n](32x256) + b1[n]); act = hh @ w2[n] + b2[n]
__global__ __launch_bounds__(256) void k_nlm(const float* __restrict__ trace,
                                             const float* __restrict__ w1,
                                             const float* __restrict__ b1,
                                             const float* __restrict__ w2,
                                             const float* __restrict__ b2,
                                             float* __restrict__ act, int t) {
  int n = blockIdx.x;
  int tid = threadIdx.x;
  int tb = tid >> 5;    // 0..7 -> b range tb*8..tb*8+8
  int tjj = tid & 31;   // 0..31 -> j = tjj + 32*jj (bank-conflict-free)
  __shared__ __align__(16) float At[32 * 68];  // [m][b]
  __shared__ __align__(16) float w1s[32 * 256];
  __shared__ float b1s[256];
  __shared__ float w2s[128];

  // trace window: contiguous [n][t+1 .. t+33][0..64] = 8KB coalesced
  const float* tw = trace + n * TRN + (t + 1) * 64;
  #pragma unroll
  for (int r = 0; r < 8; r++) {
    int idx = r * 256 + tid;  // idx = m*64 + bb
    int m = idx >> 6, bb = idx & 63;
    At[m * 68 + bb] = tw[idx];
  }
  const float4* w1n = (const float4*)(w1 + n * 8192);
  float4* w1s4 = (float4*)w1s;
  #pragma unroll
  for (int r = 0; r < 8; r++) w1s4[r * 256 + tid] = w1n[r * 256 + tid];
  b1s[tid] = b1[n * 256 + tid];
  if (tid < 128) w2s[tid] = w2[n * 128 + tid];
  __syncthreads();

  float h[8][8];
  #pragma unroll
  for (int jj = 0; jj < 8; jj++) {
    float bv = b1s[tjj + 32 * jj];
    #pragma unroll
    for (int i = 0; i < 8; i++) h[i][jj] = bv;
  }
  for (int m = 0; m < 32; m++) {
    float4 a0 = *(const float4*)(At + m * 68 + tb * 8);
    float4 a1 = *(const float4*)(At + m * 68 + tb * 8 + 4);
    float a[8] = {a0.x, a0.y, a0.z, a0.w, a1.x, a1.y, a1.z, a1.w};
    float w[8];
    #pragma unroll
    for (int jj = 0; jj < 8; jj++) w[jj] = w1s[m * 256 + tjj + 32 * jj];
    #pragma unroll
    for (int i = 0; i < 8; i++)
      #pragma unroll
      for (int jj = 0; jj < 8; jj++) h[i][jj] += a[i] * w[jj];
  }
  float b2n = b2[n];
  #pragma unroll
  for (int i = 0; i < 8; i++) {
    float p = 0.f;
    #pragma unroll
    for (int jj = 0; jj < 4; jj++) {
      float hh = h[i][jj] * sigmoidf(h[i][jj + 4]);
      p += hh * w2s[tjj + 32 * jj];
    }
    #pragma unroll
    for (int off = 16; off > 0; off >>= 1) p += __shfl_xor(p, off, 64);
    if (tjj == 0) act[(tb * 8 + i) * 1024 + n] = p + b2n;
  }
}

// fused op head: sync-out update + LN256(relu) + LN64(relu) + pred + entropy
__global__ __launch_bounds__(256) void k_op(const float* __restrict__ act,
                                            const float* __restrict__ decay,
                                            const int* __restrict__ il, const int* __restrict__ ir,
                                            float* __restrict__ aO, float* __restrict__ bO,
                                            const float* __restrict__ w1, const float* __restrict__ bb1,
                                            const float* __restrict__ g1, const float* __restrict__ bn1,
                                            const float* __restrict__ w2, const float* __restrict__ bb2,
                                            const float* __restrict__ g2, const float* __restrict__ bn2,
                                            const float* __restrict__ w3, const float* __restrict__ bb3,
                                            float* __restrict__ out, int t) {
  int b = blockIdx.x, tid = threadIdx.x;  // 256 threads
  __shared__ __align__(16) float so[512];
  __shared__ float p1s[256];
  __shared__ float qred[256];
  __shared__ float p2s[64];
  __shared__ float preds[10];
  __shared__ float2 sh[4];

  // 1) sync-out recurrence (512 elems, 2/thread)
  #pragma unroll
  for (int r = 0; r < 2; r++) {
    int o = r * 256 + tid;
    float rr = expf(-fminf(fmaxf(decay[o], 0.f), 15.f));
    float pp = act[b * 1024 + il[o]] * act[b * 1024 + ir[o]];
    float a = rr * aO[b * 512 + o] + pp;
    float bbv = rr * bO[b * 512 + o] + 1.f;
    aO[b * 512 + o] = a;
    bO[b * 512 + o] = bbv;
    so[o] = a * rsqrtf(bbv + 1e-8f);
  }
  __syncthreads();

  // 2) GEMV1: 256 outputs, K=512 (float4 weight rows; so broadcast from LDS)
  float p;
  {
    float s0 = 0.f, s1 = 0.f, s2 = 0.f, s3 = 0.f;
    const float4* wr = (const float4*)(w1 + tid * 512);
    const float4* so4 = (const float4*)so;
    for (int k = 0; k < 128; k++) {
      float4 w4 = wr[k];
      float4 sv = so4[k];
      s0 += w4.x * sv.x; s1 += w4.y * sv.y; s2 += w4.z * sv.z; s3 += w4.w * sv.w;
    }
    p = bb1[tid] + (s0 + s1) + (s2 + s3);
  }
  float2 s = block_sum2<256>(p, p * p, sh);
  {
    float mu = s.x * (1.f / 256.f);
    float var = s.y * (1.f / 256.f) - mu * mu;
    float y = (p - mu) * rsqrtf(var + 1e-5f) * g1[tid] + bn1[tid];
    p1s[tid] = fmaxf(y, 0.f);
  }
  __syncthreads();

  // 3) GEMV2: 64 outputs, K=256 split over 4 thread-groups
  {
    int o = tid & 63, tg = tid >> 6;
    const float* w2r = w2 + o * 256 + tg * 64;
    const float* pp1 = p1s + tg * 64;
    float q = 0.f;
    for (int k = 0; k < 64; k++) q += w2r[k] * pp1[k];
    qred[tid] = q;
  }
  __syncthreads();
  if (tid < 64) {
    float p2 = qred[tid] + qred[tid + 64] + qred[tid + 128] + qred[tid + 192] + bb2[tid];
    float sa = wave_sum(p2), sb = wave_sum(p2 * p2);
    float mu = sa * (1.f / 64.f);
    float var = sb * (1.f / 64.f) - mu * mu;
    float y = (p2 - mu) * rsqrtf(var + 1e-5f) * g2[tid] + bn2[tid];
    p2s[tid] = fmaxf(y, 0.f);
  }
  __syncthreads();

  // 4) GEMV3: 10 outputs, K=64; 16 lanes per output
  if (tid < 160) {
    int o = tid >> 4, j = tid & 15;
    const float* w3r = w3 + o * 64 + j * 4;
    const float* pp2 = p2s + j * 4;
    float sv = w3r[0] * pp2[0] + w3r[1] * pp2[1] + w3r[2] * pp2[2] + w3r[3] * pp2[3];
    #pragma unroll
    for (int off = 8; off; off >>= 1) sv += __shfl_xor(sv, off, 64);
    if (j == 0) {
      float pr = sv + bb3[o];
      preds[o] = pr;
      out[b * 250 + o * 25 + t] = pr;  // predictions (B, OD, T)
    }
  }
  __syncthreads();

  // 5) entropy (serial over 10, cheap)
  if (tid == 0) {
    float mx = preds[0];
    #pragma unroll
    for (int k = 1; k < 10; k++) mx = fmaxf(mx, preds[k]);
    float sum = 0.f, e[10];
    #pragma unroll
    for (int k = 0; k < 10; k++) { e[k] = expf(preds[k] - mx); sum += e[k]; }
    float ent = 0.f;
    #pragma unroll
    for (int k = 0; k < 10; k++) {
      float pr = e[k] / sum;
      ent -= pr * logf(pr + 1e-10f);
    }
    ent *= (1.f / 2.302585093f);  // / log(10)
    out[16000 + b * 50 + t] = ent;          // certainties (B, 2, T)
    out[16000 + b * 50 + 25 + t] = 1.f - ent;
  }
}

extern "C" void kernel_launch(void* const* d_in, const int* in_sizes, int n_in,
                              void* d_out, int out_size, void* d_ws, size_t ws_size,
                              hipStream_t stream) {
  const float* x        = (const float*)d_in[0];
  const float* sas      = (const float*)d_in[1];
  const float* st       = (const float*)d_in[2];
  const float* ie_w1    = (const float*)d_in[3];
  const float* ie_b1    = (const float*)d_in[4];
  const float* ie_g1    = (const float*)d_in[5];
  const float* ie_bn1   = (const float*)d_in[6];
  const float* ie_w2    = (const float*)d_in[7];
  const float* ie_b2    = (const float*)d_in[8];
  const float* ie_g2    = (const float*)d_in[9];
  const float* ie_bn2   = (const float*)d_in[10];
  const float* ie_w3    = (const float*)d_in[11];
  const float* ie_b3    = (const float*)d_in[12];
  const float* kv_w     = (const float*)d_in[13];
  const float* kv_b     = (const float*)d_in[14];
  const float* kv_g     = (const float*)d_in[15];
  const float* kv_bn    = (const float*)d_in[16];
  // d_in[17] q_w, d_in[18] q_b unused by reference
  const float* ip_w     = (const float*)d_in[19];
  const float* ip_b     = (const float*)d_in[20];
  const float* op_w     = (const float*)d_in[21];
  const float* op_b     = (const float*)d_in[22];
  const float* syn_w    = (const float*)d_in[23];
  const float* syn_b    = (const float*)d_in[24];
  const float* syn_g    = (const float*)d_in[25];
  const float* syn_bn   = (const float*)d_in[26];
  const float* nlm_w1   = (const float*)d_in[27];
  const float* nlm_b1   = (const float*)d_in[28];
  const float* nlm_w2   = (const float*)d_in[29];
  const float* nlm_b2   = (const float*)d_in[30];
  // d_in[31] decay_action unused (aA/bA dead in reference)
  const float* decay_o  = (const float*)d_in[32];
  const float* op_w1    = (const float*)d_in[33];
  const float* op_b1    = (const float*)d_in[34];
  const float* op_g1    = (const float*)d_in[35];
  const float* op_bn1   = (const float*)d_in[36];
  const float* op_w2    = (const float*)d_in[37];
  const float* op_b2    = (const float*)d_in[38];
  const float* op_g2    = (const float*)d_in[39];
  const float* op_bn2   = (const float*)d_in[40];
  const float* op_w3    = (const float*)d_in[41];
  const float* op_b3    = (const float*)d_in[42];
  const int* idx_ol     = (const int*)d_in[43];
  const int* idx_or     = (const int*)d_in[44];
  // d_in[45]/[46] idx_act_* unused (aA/bA dead)

  float* out = (float*)d_out;
  float* ws = (float*)d_ws;
  // workspace layout (floats), ~4.95M floats
  float* attn  = ws;                 // 64*512
  float* act   = attn + 32768;       // 64*1024
  float* aO    = act + 65536;        // 64*512
  float* bO    = aO + 32768;         // 64*512
  float* part  = bO + 32768;         // 8*64*2048 (also encoder temps)
  float* trace = part + 1048576;     // 1024*57*64, layout [n][col][b]

  // encoder temps live inside `part` (free until first k_syn_mm)
  float* t1  = part;                 // 64*128
  float* t2  = t1 + 8192;            // 64*64
  float* enc = t2 + 4096;            // 64*512
  float* kvt = enc + 32768;          // 64*512
  float* v   = kvt + 32768;          // 64*512

  // ---- one-time encoder ----
  k_gemv<<<2048, 256, 0, stream>>>(x, ie_w1, ie_b1, t1, 784, 128);
  k_ln<128, true><<<64, 128, 0, stream>>>(t1, ie_g1, ie_bn1, t1);
  k_gemv<<<1024, 256, 0, stream>>>(t1, ie_w2, ie_b2, t2, 128, 64);
  k_ln<64, true><<<64, 64, 0, stream>>>(t2, ie_g2, ie_bn2, t2);
  k_gemv<<<8192, 256, 0, stream>>>(t2, ie_w3, ie_b3, enc, 64, 512);
  k_gemv<<<8192, 256, 0, stream>>>(enc, kv_w, kv_b, kvt, 512, 512);
  k_ln<512, false><<<64, 512, 0, stream>>>(kvt, kv_g, kv_bn, kvt);
  k_gemv<<<8192, 256, 0, stream>>>(kvt, ip_w + 1024 * 512, ip_b + 1024, v, 512, 512);
  k_gemv<<<8192, 256, 0, stream>>>(v, op_w, op_b, attn, 512, 512);

  k_init_trace<<<8192, 256, 0, stream>>>(st, trace);
  k_init_state<<<256, 256, 0, stream>>>(sas, idx_ol, idx_or, act, aO, bO);

  for (int t = 0; t < 25; t++) {
    k_syn_mm<<<dim3(32, 8), 256, 0, stream>>>(attn, act, syn_w, part);
    k_syn_ln<<<64, 1024, 0, stream>>>(part, syn_b, syn_g, syn_bn, trace, t);
    k_nlm<<<1024, 256, 0, stream>>>(trace, nlm_w1, nlm_b1, nlm_w2, nlm_b2, act, t);
    k_op<<<64, 256, 0, stream>>>(act, decay_o, idx_ol, idx_or, aO, bO,
                                 op_w1, op_b1, op_g1, op_bn1,
                                 op_w2, op_b2, op_g2, op_bn2,
                                 op_w3, op_b3, out, t);
  }
}

// Round 3
// 1934.311 us; speedup vs baseline: 1.2542x; 1.1174x over previous
//
#include <hip/hip_runtime.h>
#include <math.h>

// Dims: B=64, N=1024, M=32, T=25, R=512, SO=512, OD=10
#define TRW 57            // trace ring width = M + T
#define TRN (TRW * 64)    // 3648 floats per n: trace layout [n][col][b]

__device__ __forceinline__ float wave_sum(float v) {
  #pragma unroll
  for (int off = 32; off; off >>= 1) v += __shfl_xor(v, off, 64);
  return v;
}

template<int NT>
__device__ __forceinline__ float2 block_sum2(float a, float b, float2* sh) {
  constexpr int NW = NT / 64;
  a = wave_sum(a); b = wave_sum(b);
  int w = threadIdx.x >> 6, l = threadIdx.x & 63;
  if (l == 0) sh[w] = make_float2(a, b);
  __syncthreads();
  float2 r = make_float2(0.f, 0.f);
  #pragma unroll
  for (int i = 0; i < NW; i++) { r.x += sh[i].x; r.y += sh[i].y; }
  __syncthreads();
  return r;
}

__device__ __forceinline__ float sigmoidf(float x) {
  return 1.f / (1.f + expf(-x));
}

// ---------------- one-time fused encoder: one block per b ----------------
__global__ __launch_bounds__(512) void k_enc(const float* __restrict__ x,
    const float* __restrict__ w1, const float* __restrict__ b1,
    const float* __restrict__ g1, const float* __restrict__ bn1,
    const float* __restrict__ w2, const float* __restrict__ b2,
    const float* __restrict__ g2, const float* __restrict__ bn2,
    const float* __restrict__ w3, const float* __restrict__ b3,
    const float* __restrict__ kvw, const float* __restrict__ kvb,
    const float* __restrict__ kvg, const float* __restrict__ kvbn,
    const float* __restrict__ ipw, const float* __restrict__ ipb,
    const float* __restrict__ opw, const float* __restrict__ opb,
    float* __restrict__ attn) {
  int b = blockIdx.x, tid = threadIdx.x, w = tid >> 6, l = tid & 63;
  __shared__ float xs[784];
  __shared__ float A[512];
  __shared__ float Bv[512];
  __shared__ float buf1[128];
  __shared__ float buf2[64];
  __shared__ float2 sh[8];
  for (int i = tid; i < 784; i += 512) xs[i] = x[b * 784 + i];
  __syncthreads();
  // L1: 128 outs, K=784
  for (int r = 0; r < 16; r++) {
    int o = r * 8 + w;
    float s = 0.f;
    for (int k = l; k < 784; k += 64) s += xs[k] * w1[o * 784 + k];
    s = wave_sum(s);
    if (l == 0) buf1[o] = s + b1[o];
  }
  __syncthreads();
  {
    float v = (tid < 128) ? buf1[tid] : 0.f;
    float2 s2 = block_sum2<512>(v, v * v, sh);
    if (tid < 128) {
      float mu = s2.x * (1.f / 128.f), var = s2.y * (1.f / 128.f) - mu * mu;
      buf1[tid] = fmaxf((v - mu) * rsqrtf(var + 1e-5f) * g1[tid] + bn1[tid], 0.f);
    }
  }
  __syncthreads();
  // L2: 64 outs, K=128
  for (int r = 0; r < 8; r++) {
    int o = r * 8 + w;
    float s = buf1[l] * w2[o * 128 + l] + buf1[l + 64] * w2[o * 128 + l + 64];
    s = wave_sum(s);
    if (l == 0) buf2[o] = s + b2[o];
  }
  __syncthreads();
  if (tid < 64) {
    float v = buf2[tid];
    float sa = wave_sum(v), sb = wave_sum(v * v);
    float mu = sa * (1.f / 64.f), var = sb * (1.f / 64.f) - mu * mu;
    buf2[tid] = fmaxf((v - mu) * rsqrtf(var + 1e-5f) * g2[tid] + bn2[tid], 0.f);
  }
  __syncthreads();
  // L3: enc (512 outs, K=64)
  for (int r = 0; r < 64; r++) {
    int o = r * 8 + w;
    float s = wave_sum(buf2[l] * w3[o * 64 + l]);
    if (l == 0) A[o] = s + b3[o];
  }
  __syncthreads();
  // kv (512 outs, K=512) + LN
  for (int r = 0; r < 64; r++) {
    int o = r * 8 + w;
    float s = 0.f;
    #pragma unroll
    for (int k = 0; k < 8; k++) s += A[l + 64 * k] * kvw[o * 512 + l + 64 * k];
    s = wave_sum(s);
    if (l == 0) Bv[o] = s + kvb[o];
  }
  __syncthreads();
  {
    float v = Bv[tid];
    float2 s2 = block_sum2<512>(v, v * v, sh);
    float mu = s2.x * (1.f / 512.f), var = s2.y * (1.f / 512.f) - mu * mu;
    Bv[tid] = (v - mu) * rsqrtf(var + 1e-5f) * kvg[tid] + kvbn[tid];
  }
  __syncthreads();
  // v = kv @ Wv^T (in_proj rows [1024:1536))
  for (int r = 0; r < 64; r++) {
    int o = r * 8 + w;
    float s = 0.f;
    #pragma unroll
    for (int k = 0; k < 8; k++) s += Bv[l + 64 * k] * ipw[(1024 + o) * 512 + l + 64 * k];
    s = wave_sum(s);
    if (l == 0) A[o] = s + ipb[1024 + o];
  }
  __syncthreads();
  // attn_out = v @ out_proj^T
  for (int r = 0; r < 64; r++) {
    int o = r * 8 + w;
    float s = 0.f;
    #pragma unroll
    for (int k = 0; k < 8; k++) s += A[l + 64 * k] * opw[o * 512 + l + 64 * k];
    s = wave_sum(s);
    if (l == 0) attn[b * 512 + o] = s + opb[o];
  }
}

// ---------------- one-time setup: trace/state init + weight transposes ----------------
__global__ void k_setup(const float* __restrict__ st, const float* __restrict__ sas,
                        const int* __restrict__ il, const int* __restrict__ ir,
                        const float* __restrict__ opw1, const float* __restrict__ opw2,
                        float* __restrict__ trace, float* __restrict__ act,
                        float* __restrict__ aO, float* __restrict__ bO,
                        float* __restrict__ w1t, float* __restrict__ w2t) {
  long i = (long)blockIdx.x * 256 + threadIdx.x;
  if (i < 2097152) {  // trace init: [n][j][b] = st[n][j]
    int b = (int)(i & 63), j = (int)((i >> 6) & 31), n = (int)(i >> 11);
    trace[n * TRN + j * 64 + b] = st[n * 32 + j];
    return;
  }
  i -= 2097152;
  if (i < 65536) {  // act[b][n] = sas[n]
    act[i] = sas[i & 1023];
    return;
  }
  i -= 65536;
  if (i < 32768) {  // aO/bO
    int o = (int)(i & 511);
    aO[i] = sas[il[o]] * sas[ir[o]];
    bO[i] = 1.f;
    return;
  }
  i -= 32768;
  if (i < 131072) {  // w1t[k*256+o] = opw1[o*512+k]
    int o = (int)(i & 255), k = (int)(i >> 8);
    w1t[i] = opw1[o * 512 + k];
    return;
  }
  i -= 131072;
  if (i < 16384) {  // w2t[k*64+o] = opw2[o*256+k]
    int o = (int)(i & 63), k = (int)(i >> 6);
    w2t[i] = opw2[o * 256 + k];
  }
}

// ---------------- op head (device body, 256 threads/block) ----------------
__device__ void op_body(int b, int t, const float* __restrict__ act,
                        const float* __restrict__ decay,
                        const int* __restrict__ il, const int* __restrict__ ir,
                        float* __restrict__ aO, float* __restrict__ bO,
                        const float* __restrict__ w1t, const float* __restrict__ bb1,
                        const float* __restrict__ g1, const float* __restrict__ bn1,
                        const float* __restrict__ w2t, const float* __restrict__ bb2,
                        const float* __restrict__ g2, const float* __restrict__ bn2,
                        const float* __restrict__ w3, const float* __restrict__ bb3,
                        float* __restrict__ out,
                        float* so, float* p1s, float* qred, float* p2s,
                        float* preds, float2* sh) {
  int tid = threadIdx.x;
  #pragma unroll
  for (int r = 0; r < 2; r++) {
    int o = r * 256 + tid;
    float rr = expf(-fminf(fmaxf(decay[o], 0.f), 15.f));
    float pp = act[b * 1024 + il[o]] * act[b * 1024 + ir[o]];
    float a = rr * aO[b * 512 + o] + pp;
    float bbv = rr * bO[b * 512 + o] + 1.f;
    aO[b * 512 + o] = a;
    bO[b * 512 + o] = bbv;
    so[o] = a * rsqrtf(bbv + 1e-8f);
  }
  __syncthreads();
  // GEMV1: 256 outs, K=512, coalesced k-major weights
  float p = bb1[tid];
  #pragma unroll 8
  for (int k = 0; k < 512; k++) p += so[k] * w1t[k * 256 + tid];
  float2 s = block_sum2<256>(p, p * p, sh);
  {
    float mu = s.x * (1.f / 256.f), var = s.y * (1.f / 256.f) - mu * mu;
    p1s[tid] = fmaxf((p - mu) * rsqrtf(var + 1e-5f) * g1[tid] + bn1[tid], 0.f);
  }
  __syncthreads();
  // GEMV2: 64 outs, K=256 split over 4 groups, coalesced
  {
    int o = tid & 63, tg = tid >> 6;
    float q = 0.f;
    #pragma unroll 4
    for (int j = 0; j < 64; j++) {
      int k = tg * 64 + j;
      q += p1s[k] * w2t[k * 64 + o];
    }
    qred[tid] = q;
  }
  __syncthreads();
  if (tid < 64) {
    float p2 = qred[tid] + qred[tid + 64] + qred[tid + 128] + qred[tid + 192] + bb2[tid];
    float sa = wave_sum(p2), sb = wave_sum(p2 * p2);
    float mu = sa * (1.f / 64.f), var = sb * (1.f / 64.f) - mu * mu;
    float y = (p2 - mu) * rsqrtf(var + 1e-5f) * g2[tid] + bn2[tid];
    p2s[tid] = fmaxf(y, 0.f);
  }
  __syncthreads();
  if (tid < 160) {
    int o = tid >> 4, j = tid & 15;
    const float* w3r = w3 + o * 64 + j * 4;
    const float* pp2 = p2s + j * 4;
    float sv = w3r[0] * pp2[0] + w3r[1] * pp2[1] + w3r[2] * pp2[2] + w3r[3] * pp2[3];
    #pragma unroll
    for (int off = 8; off; off >>= 1) sv += __shfl_xor(sv, off, 64);
    if (j == 0) {
      float pr = sv + bb3[o];
      preds[o] = pr;
      out[b * 250 + o * 25 + t] = pr;
    }
  }
  __syncthreads();
  if (tid == 0) {
    float mx = preds[0];
    #pragma unroll
    for (int k = 1; k < 10; k++) mx = fmaxf(mx, preds[k]);
    float sum = 0.f, e[10];
    #pragma unroll
    for (int k = 0; k < 10; k++) { e[k] = expf(preds[k] - mx); sum += e[k]; }
    float ent = 0.f;
    #pragma unroll
    for (int k = 0; k < 10; k++) {
      float pr = e[k] / sum;
      ent -= pr * logf(pr + 1e-10f);
    }
    ent *= (1.f / 2.302585093f);
    out[16000 + b * 50 + t] = ent;
    out[16000 + b * 50 + 25 + t] = 1.f - ent;
  }
}

// ---------------- fused: syn GEMM (blocks 0..511) + op(t-1) (blocks 512..575) ----
__global__ __launch_bounds__(256) void k_F(const float* __restrict__ attn,
    const float* __restrict__ act, const float* __restrict__ synw,
    float* __restrict__ part,
    const float* __restrict__ decay, const int* __restrict__ il, const int* __restrict__ ir,
    float* __restrict__ aO, float* __restrict__ bO,
    const float* __restrict__ w1t, const float* __restrict__ bb1,
    const float* __restrict__ g1, const float* __restrict__ bn1,
    const float* __restrict__ w2t, const float* __restrict__ bb2,
    const float* __restrict__ g2, const float* __restrict__ bn2,
    const float* __restrict__ w3, const float* __restrict__ bb3,
    float* __restrict__ out, int t) {
  __shared__ __align__(16) float pre_t[32 * 68];
  __shared__ __align__(16) float w_lds[32 * 68];
  __shared__ __align__(16) float so[512];
  __shared__ float p1s[256];
  __shared__ float qred[256];
  __shared__ float p2s[64];
  __shared__ float preds[10];
  __shared__ float2 sh[4];
  int bid = blockIdx.x;
  if (bid >= 512) {
    if (t > 0)
      op_body(bid - 512, t - 1, act, decay, il, ir, aO, bO, w1t, bb1, g1, bn1,
              w2t, bb2, g2, bn2, w3, bb3, out, so, p1s, qred, p2s, preds, sh);
    return;
  }
  int ct = bid & 31;   // column tile (64 cols)
  int kc = bid >> 5;   // 0..15, K-chunk of 96
  int tid = threadIdx.x;
  int tb = tid >> 4, tc = tid & 15;
  int b0 = tb * 4, c0 = tc * 4;
  float acc[4][4];
  #pragma unroll
  for (int i = 0; i < 4; i++)
    #pragma unroll
    for (int j = 0; j < 4; j++) acc[i][j] = 0.f;

  for (int kt = 0; kt < 96; kt += 32) {
    int k0 = kc * 96 + kt;
    #pragma unroll
    for (int r = 0; r < 8; r++) {
      int idx = r * 256 + tid;  // < 2048
      int kk = idx & 31;
      int bb = idx >> 5;
      int kg = k0 + kk;
      float pv = (kg < 512) ? attn[bb * 512 + kg] : act[bb * 1024 + (kg - 512)];
      pre_t[kk * 68 + bb] = pv;
      w_lds[kk * 68 + bb] = synw[(ct * 64 + bb) * 1536 + kg];
    }
    __syncthreads();
    #pragma unroll 8
    for (int kk = 0; kk < 32; kk++) {
      float4 av = *(const float4*)(pre_t + kk * 68 + b0);
      float4 wv = *(const float4*)(w_lds + kk * 68 + c0);
      float a[4] = {av.x, av.y, av.z, av.w};
      float w[4] = {wv.x, wv.y, wv.z, wv.w};
      #pragma unroll
      for (int i = 0; i < 4; i++)
        #pragma unroll
        for (int j = 0; j < 4; j++) acc[i][j] += a[i] * w[j];
    }
    __syncthreads();
  }
  float* pb = part + kc * (64 * 2048);
  #pragma unroll
  for (int i = 0; i < 4; i++) {
    float4 st4 = make_float4(acc[i][0], acc[i][1], acc[i][2], acc[i][3]);
    *(float4*)(pb + (b0 + i) * 2048 + ct * 64 + c0) = st4;
  }
}

__global__ __launch_bounds__(256) void k_op_tail(const float* __restrict__ act,
    const float* __restrict__ decay, const int* __restrict__ il, const int* __restrict__ ir,
    float* __restrict__ aO, float* __restrict__ bO,
    const float* __restrict__ w1t, const float* __restrict__ bb1,
    const float* __restrict__ g1, const float* __restrict__ bn1,
    const float* __restrict__ w2t, const float* __restrict__ bb2,
    const float* __restrict__ g2, const float* __restrict__ bn2,
    const float* __restrict__ w3, const float* __restrict__ bb3,
    float* __restrict__ out) {
  __shared__ __align__(16) float so[512];
  __shared__ float p1s[256];
  __shared__ float qred[256];
  __shared__ float p2s[64];
  __shared__ float preds[10];
  __shared__ float2 sh[4];
  op_body(blockIdx.x, 24, act, decay, il, ir, aO, bO, w1t, bb1, g1, bn1,
          w2t, bb2, g2, bn2, w3, bb3, out, so, p1s, qred, p2s, preds, sh);
}

// sum 16 partials + bias -> GLU -> LN(1024) -> ns[b][n] (coalesced)
__global__ __launch_bounds__(1024) void k_syn_ln(const float* __restrict__ part,
                                                 const float* __restrict__ synb,
                                                 const float* __restrict__ sg,
                                                 const float* __restrict__ sbn,
                                                 float* __restrict__ ns) {
  __shared__ float2 sh[16];
  int b = blockIdx.x, n = threadIdx.x;
  float a = synb[n], g = synb[n + 1024];
  #pragma unroll
  for (int kc = 0; kc < 16; kc++) {
    const float* pb = part + kc * (64 * 2048) + b * 2048;
    a += pb[n];
    g += pb[n + 1024];
  }
  float val = a * sigmoidf(g);
  float2 s = block_sum2<1024>(val, val * val, sh);
  float mu = s.x * (1.f / 1024.f);
  float var = s.y * (1.f / 1024.f) - mu * mu;
  ns[b * 1024 + n] = (val - mu) * rsqrtf(var + 1e-5f) * sg[n] + sbn[n];
}

// per-n NLM; stages window from own trace row + ns column; writes new col to trace
__global__ __launch_bounds__(256) void k_nlm(const float* __restrict__ trace_c,
                                             float* __restrict__ trace,
                                             const float* __restrict__ ns,
                                             const float* __restrict__ w1,
                                             const float* __restrict__ b1,
                                             const float* __restrict__ w2,
                                             const float* __restrict__ b2,
                                             float* __restrict__ act, int t) {
  int n = blockIdx.x;
  int tid = threadIdx.x;
  int tb = tid >> 5;
  int tjj = tid & 31;
  __shared__ __align__(16) float At[32 * 68];  // [m][b]
  __shared__ __align__(16) float w1s[32 * 256];
  __shared__ float b1s[256];
  __shared__ float w2s[128];

  // m = 0..30 from trace cols t+1..t+31 (contiguous 1984 floats)
  const float4* tw4 = (const float4*)(trace_c + n * TRN + (t + 1) * 64);
  #pragma unroll
  for (int r = 0; r < 2; r++) {
    int idx = r * 256 + tid;
    if (idx < 496) {
      float4 f4 = tw4[idx];
      int fo = idx * 4;
      int m = fo >> 6, bb = fo & 63;
      *(float4*)(At + m * 68 + bb) = f4;
    }
  }
  // m = 31 from ns; also persist as trace col 32+t (block owns trace[n])
  if (tid < 64) {
    float v = ns[tid * 1024 + n];
    At[31 * 68 + tid] = v;
    trace[n * TRN + (32 + t) * 64 + tid] = v;
  }
  const float4* w1n = (const float4*)(w1 + n * 8192);
  float4* w1s4 = (float4*)w1s;
  #pragma unroll
  for (int r = 0; r < 8; r++) w1s4[r * 256 + tid] = w1n[r * 256 + tid];
  b1s[tid] = b1[n * 256 + tid];
  if (tid < 128) w2s[tid] = w2[n * 128 + tid];
  __syncthreads();

  float h[8][8];
  #pragma unroll
  for (int jj = 0; jj < 8; jj++) {
    float bv = b1s[tjj + 32 * jj];
    #pragma unroll
    for (int i = 0; i < 8; i++) h[i][jj] = bv;
  }
  for (int m = 0; m < 32; m++) {
    float4 a0 = *(const float4*)(At + m * 68 + tb * 8);
    float4 a1 = *(const float4*)(At + m * 68 + tb * 8 + 4);
    float a[8] = {a0.x, a0.y, a0.z, a0.w, a1.x, a1.y, a1.z, a1.w};
    float w[8];
    #pragma unroll
    for (int jj = 0; jj < 8; jj++) w[jj] = w1s[m * 256 + tjj + 32 * jj];
    #pragma unroll
    for (int i = 0; i < 8; i++)
      #pragma unroll
      for (int jj = 0; jj < 8; jj++) h[i][jj] += a[i] * w[jj];
  }
  float b2n = b2[n];
  #pragma unroll
  for (int i = 0; i < 8; i++) {
    float p = 0.f;
    #pragma unroll
    for (int jj = 0; jj < 4; jj++) {
      float hh = h[i][jj] * sigmoidf(h[i][jj + 4]);
      p += hh * w2s[tjj + 32 * jj];
    }
    #pragma unroll
    for (int off = 16; off > 0; off >>= 1) p += __shfl_xor(p, off, 64);
    if (tjj == 0) act[(tb * 8 + i) * 1024 + n] = p + b2n;
  }
}

extern "C" void kernel_launch(void* const* d_in, const int* in_sizes, int n_in,
                              void* d_out, int out_size, void* d_ws, size_t ws_size,
                              hipStream_t stream) {
  const float* x        = (const float*)d_in[0];
  const float* sas      = (const float*)d_in[1];
  const float* st       = (const float*)d_in[2];
  const float* ie_w1    = (const float*)d_in[3];
  const float* ie_b1    = (const float*)d_in[4];
  const float* ie_g1    = (const float*)d_in[5];
  const float* ie_bn1   = (const float*)d_in[6];
  const float* ie_w2    = (const float*)d_in[7];
  const float* ie_b2    = (const float*)d_in[8];
  const float* ie_g2    = (const float*)d_in[9];
  const float* ie_bn2   = (const float*)d_in[10];
  const float* ie_w3    = (const float*)d_in[11];
  const float* ie_b3    = (const float*)d_in[12];
  const float* kv_w     = (const float*)d_in[13];
  const float* kv_b     = (const float*)d_in[14];
  const float* kv_g     = (const float*)d_in[15];
  const float* kv_bn    = (const float*)d_in[16];
  const float* ip_w     = (const float*)d_in[19];
  const float* ip_b     = (const float*)d_in[20];
  const float* op_w     = (const float*)d_in[21];
  const float* op_b     = (const float*)d_in[22];
  const float* syn_w    = (const float*)d_in[23];
  const float* syn_b    = (const float*)d_in[24];
  const float* syn_g    = (const float*)d_in[25];
  const float* syn_bn   = (const float*)d_in[26];
  const float* nlm_w1   = (const float*)d_in[27];
  const float* nlm_b1   = (const float*)d_in[28];
  const float* nlm_w2   = (const float*)d_in[29];
  const float* nlm_b2   = (const float*)d_in[30];
  const float* decay_o  = (const float*)d_in[32];
  const float* op_w1    = (const float*)d_in[33];
  const float* op_b1    = (const float*)d_in[34];
  const float* op_g1    = (const float*)d_in[35];
  const float* op_bn1   = (const float*)d_in[36];
  const float* op_w2    = (const float*)d_in[37];
  const float* op_b2    = (const float*)d_in[38];
  const float* op_g2    = (const float*)d_in[39];
  const float* op_bn2   = (const float*)d_in[40];
  const float* op_w3    = (const float*)d_in[41];
  const float* op_b3    = (const float*)d_in[42];
  const int* idx_ol     = (const int*)d_in[43];
  const int* idx_or     = (const int*)d_in[44];

  float* out = (float*)d_out;
  float* ws = (float*)d_ws;
  float* attn  = ws;                 // 32768
  float* act   = attn + 32768;       // 65536
  float* aO    = act + 65536;        // 32768
  float* bO    = aO + 32768;         // 32768
  float* ns    = bO + 32768;         // 65536
  float* w1t   = ns + 65536;         // 131072
  float* w2t   = w1t + 131072;       // 16384
  float* part  = w2t + 16384;        // 16*64*2048 = 2097152
  float* trace = part + 2097152;     // 1024*3648 = 3735552  (~25 MB total)

  k_enc<<<64, 512, 0, stream>>>(x, ie_w1, ie_b1, ie_g1, ie_bn1,
                                ie_w2, ie_b2, ie_g2, ie_bn2, ie_w3, ie_b3,
                                kv_w, kv_b, kv_g, kv_bn, ip_w, ip_b, op_w, op_b, attn);
  k_setup<<<9152, 256, 0, stream>>>(st, sas, idx_ol, idx_or, op_w1, op_w2,
                                    trace, act, aO, bO, w1t, w2t);

  for (int t = 0; t < 25; t++) {
    k_F<<<576, 256, 0, stream>>>(attn, act, syn_w, part,
                                 decay_o, idx_ol, idx_or, aO, bO,
                                 w1t, op_b1, op_g1, op_bn1,
                                 w2t, op_b2, op_g2, op_bn2,
                                 op_w3, op_b3, out, t);
    k_syn_ln<<<64, 1024, 0, stream>>>(part, syn_b, syn_g, syn_bn, ns);
    k_nlm<<<1024, 256, 0, stream>>>(trace, trace, ns, nlm_w1, nlm_b1,
                                    nlm_w2, nlm_b2, act, t);
  }
  k_op_tail<<<64, 256, 0, stream>>>(act, decay_o, idx_ol, idx_or, aO, bO,
                                    w1t, op_b1, op_g1, op_bn1,
                                    w2t, op_b2, op_g2, op_bn2,
                                    op_w3, op_b3, out);
}